// Round 13
// baseline (293.049 us; speedup 1.0000x reference)
//
#include <hip/hip_runtime.h>
#include <hip/hip_bf16.h>

typedef unsigned short u16;

#define Bb  128
#define Ss  200
#define Tt  199   // S-1
#define NQq 10000
#define NCc 500
#define CHK 16    // scan chunk (steps staged per refill)
#define NCH 13    // ceil(199/16)

__device__ inline float bf2f(u16 u) {
    union { unsigned int i; float f; } x;
    x.i = ((unsigned int)u) << 16;
    return x.f;
}

// mode m: 1 = buffers hold fp32, 0 = buffers hold bf16
__device__ inline float ldf(const void* p, int i, int m) {
    if (m) return ((const float*)p)[i];
    return bf2f(((const u16*)p)[i]);
}

__device__ inline void stf(void* p, int i, int m, float v) {
    if (m) ((float*)p)[i] = v;
    else ((__hip_bfloat16*)p)[i] = __float2bfloat16(v);
}

__device__ inline int clampi(int v, int lo, int hi) {
    return v < lo ? lo : (v > hi ? hi : v);
}

__device__ inline float wave_red(float v) {
#pragma unroll
    for (int m = 32; m >= 1; m >>= 1) v += __shfl_xor(v, m);
    return v;
}

__device__ inline float4 f4add(float4 a, float4 b) {
    return make_float4(a.x + b.x, a.y + b.y, a.z + b.z, a.w + b.w);
}
__device__ inline float4 f4fma(float s, float4 a, float4 b) {
    return make_float4(fmaf(s, a.x, b.x), fmaf(s, a.y, b.y),
                       fmaf(s, a.z, b.z), fmaf(s, a.w, b.w));
}

// per-block inline dtype detection: scan first 256 u16 of Eq as bf16.
__device__ inline int detect_mode(const void* Eq) {
    const u16* q = (const u16*)Eq;
    const int l = threadIdx.x & 63;
    float mx = 0.f;
#pragma unroll
    for (int k = 0; k < 4; ++k) {
        float a = fabsf(bf2f(q[l * 4 + k]));
        if (!(a == a)) a = 3.0e38f;
        mx = fmaxf(mx, a);
    }
#pragma unroll
    for (int s = 32; s >= 1; s >>= 1) mx = fmaxf(mx, __shfl_xor(mx, s));
    return (mx > 1.0e6f) ? 1 : 0;
}

// load a flat 4096-element (32x128) tile from a mode-typed matrix into LDS
__device__ inline void load_tile_4096(float* dst, const void* src, int base,
                                      int tid, int m) {
    if (m) {
        const float4* s = (const float4*)((const float*)src + base);
        float4* d = (float4*)dst;
#pragma unroll
        for (int k = 0; k < 4; ++k) d[tid + k * 256] = s[tid + k * 256];
    } else {
        const u16* s = (const u16*)src + base;
#pragma unroll
        for (int k = 0; k < 4; ++k) {
            const int idx = (tid + k * 256) * 4;
            uint2 v = *(const uint2*)(s + idx);
            float* d = dst + idx;
            d[0] = bf2f((u16)(v.x & 0xffff)); d[1] = bf2f((u16)(v.x >> 16));
            d[2] = bf2f((u16)(v.y & 0xffff)); d[3] = bf2f((u16)(v.y >> 16));
        }
    }
}

// ---------------- K1: everything-parallel prep, ONE launch -----------------
// job<313: chained GEMM  PA_q/PF_q = (Eq@Wf_top) @ {WA1, Wg3}  (t32 in LDS)
// 313: vA/vF bias vectors | 314..413: PA_ut/PF_it | 414..425: PA_ha
// 426..2925: per-question qdm/qd10 (inline concept norms)
__global__ __launch_bounds__(256) void k_prep(
    const void* Eq, const void* Eqd, const void* Wf, const void* Wa, const void* Wg,
    const void* bfu, const void* ba, const void* bg,
    const void* Eut, const void* Eha, const void* Eit, const void* Ec,
    const int* q2c, const int* q2cm,
    float* vA0, float* vA1, float* vF0, float* vF1,
    float* PA_ut, float* PA_ha, float* PF_it, float* qdm, float* qd10,
    float* PA_q, float* PF_q) {
    const int m = detect_mode(Eq);
    const int job = blockIdx.x, tid = threadIdx.x;
    __shared__ __align__(16) float smem[12416];   // 48.5 KB, partitioned per job
    if (job < 313) {
        float* t32s = smem;            // [32][132]
        float* At   = smem + 4224;     // [32][36]   (stage 1)
        float* BtW  = smem + 5376;     // [32][128]  (stage 1)
        float* Bt0  = smem + 4224;     // [32][128]  (stage 2 overlay)
        float* Bt1  = smem + 8320;     // [32][128]
        const int r0 = job * 32;
        const int tx = tid & 15, ty = tid >> 4;
        // ---- stage 1: t32 = Eq_tile(32x128) @ Wf_top(128x128) ----
        float accT[2][8];
#pragma unroll
        for (int j = 0; j < 2; ++j)
#pragma unroll
            for (int i = 0; i < 8; ++i) accT[j][i] = 0.f;
        for (int ks = 0; ks < 4; ++ks) {
            {   // A tile from Eq: 32 rows x 32 k, 4 elements/thread
                const int row = tid >> 3, seg = tid & 7;
                const int q = clampi(r0 + row, 0, NQq - 1);
                const int ei = q * 128 + ks * 32 + seg * 4;
                float* dst = At + row * 36 + seg * 4;
                if (m) {
                    float4 v = *(const float4*)((const float*)Eq + ei);
                    dst[0] = v.x; dst[1] = v.y; dst[2] = v.z; dst[3] = v.w;
                } else {
                    uint2 v = *(const uint2*)((const u16*)Eq + ei);
                    dst[0] = bf2f((u16)(v.x & 0xffff)); dst[1] = bf2f((u16)(v.x >> 16));
                    dst[2] = bf2f((u16)(v.y & 0xffff)); dst[3] = bf2f((u16)(v.y >> 16));
                }
            }
            load_tile_4096(BtW, Wf, ks * 32 * 128, tid, m);
            __syncthreads();
#pragma unroll
            for (int kk = 0; kk < 32; kk += 4) {
                float a_[2][4];
                *(float4*)&a_[0][0] = *(const float4*)(At + (ty * 2 + 0) * 36 + kk);
                *(float4*)&a_[1][0] = *(const float4*)(At + (ty * 2 + 1) * 36 + kk);
#pragma unroll
                for (int q4 = 0; q4 < 4; ++q4) {
                    float4 b0 = *(const float4*)(BtW + (kk + q4) * 128 + tx * 8);
                    float4 b1 = *(const float4*)(BtW + (kk + q4) * 128 + tx * 8 + 4);
#pragma unroll
                    for (int j = 0; j < 2; ++j) {
                        const float av = a_[j][q4];
                        accT[j][0] += av * b0.x; accT[j][1] += av * b0.y;
                        accT[j][2] += av * b0.z; accT[j][3] += av * b0.w;
                        accT[j][4] += av * b1.x; accT[j][5] += av * b1.y;
                        accT[j][6] += av * b1.z; accT[j][7] += av * b1.w;
                    }
                }
            }
            __syncthreads();
        }
#pragma unroll
        for (int j = 0; j < 2; ++j) {
            const int row = ty * 2 + j;
            *(float4*)(t32s + row * 132 + tx * 8) =
                make_float4(accT[j][0], accT[j][1], accT[j][2], accT[j][3]);
            *(float4*)(t32s + row * 132 + tx * 8 + 4) =
                make_float4(accT[j][4], accT[j][5], accT[j][6], accT[j][7]);
        }
        __syncthreads();
        // ---- stage 2: PA = t32 @ WA1, PF = t32 @ Wg3 ----
        float acc0[2][8], acc1[2][8];
#pragma unroll
        for (int j = 0; j < 2; ++j)
#pragma unroll
            for (int i = 0; i < 8; ++i) { acc0[j][i] = 0.f; acc1[j][i] = 0.f; }
        for (int ks2 = 0; ks2 < 4; ++ks2) {
            load_tile_4096(Bt0, Wa, ks2 * 32 * 128, tid, m);
            load_tile_4096(Bt1, Wg, 256 * 128 + ks2 * 32 * 128, tid, m);
            __syncthreads();
#pragma unroll
            for (int kk = 0; kk < 32; kk += 4) {
                float a_[2][4];
                *(float4*)&a_[0][0] =
                    *(const float4*)(t32s + (ty * 2 + 0) * 132 + ks2 * 32 + kk);
                *(float4*)&a_[1][0] =
                    *(const float4*)(t32s + (ty * 2 + 1) * 132 + ks2 * 32 + kk);
#pragma unroll
                for (int q4 = 0; q4 < 4; ++q4) {
                    float4 b0 = *(const float4*)(Bt0 + (kk + q4) * 128 + tx * 8);
                    float4 b1 = *(const float4*)(Bt0 + (kk + q4) * 128 + tx * 8 + 4);
                    float4 c0 = *(const float4*)(Bt1 + (kk + q4) * 128 + tx * 8);
                    float4 c1 = *(const float4*)(Bt1 + (kk + q4) * 128 + tx * 8 + 4);
#pragma unroll
                    for (int j = 0; j < 2; ++j) {
                        const float av = a_[j][q4];
                        acc0[j][0] += av * b0.x; acc0[j][1] += av * b0.y;
                        acc0[j][2] += av * b0.z; acc0[j][3] += av * b0.w;
                        acc0[j][4] += av * b1.x; acc0[j][5] += av * b1.y;
                        acc0[j][6] += av * b1.z; acc0[j][7] += av * b1.w;
                        acc1[j][0] += av * c0.x; acc1[j][1] += av * c0.y;
                        acc1[j][2] += av * c0.z; acc1[j][3] += av * c0.w;
                        acc1[j][4] += av * c1.x; acc1[j][5] += av * c1.y;
                        acc1[j][6] += av * c1.z; acc1[j][7] += av * c1.w;
                    }
                }
            }
            __syncthreads();
        }
#pragma unroll
        for (int j = 0; j < 2; ++j) {
            const int q = r0 + ty * 2 + j;
            if (q < NQq) {
                float* oa = PA_q + q * 128 + tx * 8;
                float* of = PF_q + q * 128 + tx * 8;
#pragma unroll
                for (int i = 0; i < 8; ++i) { oa[i] = acc0[j][i]; of[i] = acc1[j][i]; }
            }
        }
    } else if (job == 313) {    // vA0/vA1 (threads<128), vF0/vF1 (>=128)
        const int col = tid & 127;
        if (tid < 128) {
            float s = 0.f;
            for (int r2 = 0; r2 < 128; ++r2) s += ldf(Wf, (128 + r2) * 128 + col, m);
            smem[col] = s;      // cs2
        }
        __syncthreads();
        float a0 = 0.f, a1 = 0.f;
        if (tid < 128) {
            for (int j = 0; j < 128; ++j) {
                const float wv = ldf(Wa, j * 128 + col, m);
                a0 += ldf(bfu, j, m) * wv;
                a1 += smem[j] * wv;
            }
            vA0[col] = a0 + ldf(ba, col, m);
            vA1[col] = a1;
        } else {
            for (int j = 0; j < 128; ++j) {
                const float wv = ldf(Wg, (256 + j) * 128 + col, m);
                a0 += ldf(bfu, j, m) * wv;
                a1 += smem[j] * wv;
            }
            vF0[col] = a0 + ldf(bg, col, m);
            vF1[col] = a1;
        }
    } else if (job < 414) {     // PA_ut row (threads<128) / PF_it row (>=128)
        const int r = job - 314, col = tid & 127;
        float acc = 0.f;
        if (tid < 128) {
            for (int j = 0; j < 128; ++j)
                acc += ldf(Eut, r * 128 + j, m) * ldf(Wa, (128 + j) * 128 + col, m);
            PA_ut[r * 128 + col] = acc;
        } else {
            for (int j = 0; j < 128; ++j)
                acc += ldf(Eit, r * 128 + j, m) * ldf(Wg, (128 + j) * 128 + col, m);
            PF_it[r * 128 + col] = acc;
        }
    } else if (job < 426) {     // PA_ha rows 0..11
        const int r = job - 414;
        if (tid < 128) {
            float acc = 0.f;
            for (int j = 0; j < 128; ++j)
                acc += ldf(Eha, r * 128 + j, m) * ldf(Wa, (256 + j) * 128 + tid, m);
            PA_ha[r * 128 + tid] = acc;
        }
    } else {                    // p2q with inline concept norms
        const int wv = tid >> 6, lane = tid & 63;
        const int q = (job - 426) * 4 + wv;   // 0..9999
        const float qa = ldf(Eq, q * 128 + lane, m);
        const float qb = ldf(Eq, q * 128 + 64 + lane, m);
        const float nqc = fmaxf(sqrtf(wave_red(qa * qa + qb * qb)), 1e-8f);
        const int4 cc = ((const int4*)q2c)[q];
        const int4 mm = ((const int4*)q2cm)[q];
        const int cks[4] = {clampi(cc.x, 0, NCc - 1), clampi(cc.y, 0, NCc - 1),
                            clampi(cc.z, 0, NCc - 1), clampi(cc.w, 0, NCc - 1)};
        const int ms[4]  = {mm.x, mm.y, mm.z, mm.w};
        float qs = 0.f;
#pragma unroll
        for (int k = 0; k < 4; ++k) {
            const int ck = cks[k];
            const float ea = ldf(Ec, ck * 128 + lane, m);
            const float eb = ldf(Ec, ck * 128 + 64 + lane, m);
            const float dot = wave_red(qa * ea + qb * eb);
            const float nn = fmaxf(sqrtf(wave_red(ea * ea + eb * eb)), 1e-8f);
            qs += (float)ms[k] * (0.5f * dot / (nqc * nn) + 0.5f);
        }
        if (lane == 0) {
            qdm[q] = qs;
            qd10[q] = 10.f / (1.f + __expf(-ldf(Eqd, q, m)));
        }
    }
}

// ---------------- K2: scan + fused per-chunk epilogue ----------------------
// Scan step loop is R8-exact (77 us plateau — do not touch). After each
// chunk's 16 steps, the consumed st_ab staging buffer receives the chunk's
// lc history (each wave writes only its own dd columns — no new hazard),
// then each wave epilogues 4 of the 16 rows entirely in-block. Removes the
// separate p5 launch, the lc_seq global buffer, and its 25 MB of traffic.
__global__ __launch_bounds__(256) void k_scan(
    const int* q_seq, const int* ut_seq, const int* ha_seq, const int* it_seq,
    const int* c_seq, const int* q2c, const int* q2cm,
    const void* Eq, const void* Ec, const void* Wg, const void* L0,
    const float* PA_q, const float* PA_ut, const float* PA_ha,
    const float* PF_q, const float* PF_it,
    const float* vA0, const float* vA1, const float* vF0, const float* vF1,
    const float* qdm, const float* qd10, void* out) {
    const int m = detect_mode(Eq);
    const int b = blockIdx.x;
    const int tid = threadIdx.x;
    const int wv = tid >> 6, l = tid & 63;
    const int d0 = 2 * l;
    const int ib = wv << 5;
    const int dd = ib + (l & 31);

    __shared__ float part[2][4][128];
    __shared__ float st_ab[CHK * 128];
    __shared__ float st_pf[CHK * 128];

    float wA[32], wB[32];
#pragma unroll
    for (int k = 0; k < 32; ++k) {
        wA[k] = ldf(Wg, (ib + k) * 128 + d0, m);
        wB[k] = ldf(Wg, (ib + k) * 128 + d0 + 1, m);
    }
    float lc = (l < 32) ? ldf(L0, b * 128 + dd, m) : 0.f;

    const int srow = tid >> 4, seg = tid & 15;
    const int off8 = seg * 8;
    const float4 A0a = *(const float4*)(vA0 + off8), A0b = *(const float4*)(vA0 + off8 + 4);
    const float4 A1a = *(const float4*)(vA1 + off8), A1b = *(const float4*)(vA1 + off8 + 4);
    const float4 F0a = *(const float4*)(vF0 + off8), F0b = *(const float4*)(vF0 + off8 + 4);
    const float4 F1a = *(const float4*)(vF1 + off8), F1b = *(const float4*)(vF1 + off8 + 4);

    float4 qa0, qa1, ua0, ua1, ga0, ga1, qf0, qf1, if0, if1;
    float cf;
#define LOAD_CHUNK(C)                                                          \
    {                                                                          \
        int tt = (C) * CHK + srow; if (tt > Tt - 1) tt = Tt - 1;               \
        const int base = b * Ss + tt;                                          \
        const int qt = clampi(q_seq[base], 0, NQq - 1);                        \
        const int ut = clampi(ut_seq[base], 0, 99);                            \
        const int ha = clampi(ha_seq[base], 0, 11);                            \
        const int it = clampi(it_seq[base], 0, 99);                            \
        cf = (float)c_seq[base];                                               \
        const float* pq = PA_q + qt * 128 + off8;                              \
        qa0 = *(const float4*)pq; qa1 = *(const float4*)(pq + 4);              \
        const float* pu = PA_ut + ut * 128 + off8;                             \
        ua0 = *(const float4*)pu; ua1 = *(const float4*)(pu + 4);              \
        const float* ph = PA_ha + ha * 128 + off8;                             \
        ga0 = *(const float4*)ph; ga1 = *(const float4*)(ph + 4);              \
        const float* pf = PF_q + qt * 128 + off8;                              \
        qf0 = *(const float4*)pf; qf1 = *(const float4*)(pf + 4);              \
        const float* pi = PF_it + it * 128 + off8;                             \
        if0 = *(const float4*)pi; if1 = *(const float4*)(pi + 4);              \
    }

    LOAD_CHUNK(0)
    float lcbuf[CHK];
    int par = 0;

    for (int c = 0; c < NCH; ++c) {
        __syncthreads();   // prior chunk's st readers (scan + epilogue) done
        {   // publish staged chunk c
            float4 ab0 = f4fma(cf, A1a, f4add(f4add(qa0, ua0), f4add(ga0, A0a)));
            float4 ab1 = f4fma(cf, A1b, f4add(f4add(qa1, ua1), f4add(ga1, A0b)));
            float4 pf0 = f4fma(cf, F1a, f4add(qf0, f4add(if0, F0a)));
            float4 pf1 = f4fma(cf, F1b, f4add(qf1, f4add(if1, F0b)));
            float4* sa = (float4*)(st_ab + srow * 128 + off8);
            sa[0] = ab0; sa[1] = ab1;
            float4* sp = (float4*)(st_pf + srow * 128 + off8);
            sp[0] = pf0; sp[1] = pf1;
        }
        if (c + 1 < NCH) LOAD_CHUNK(c + 1)
        __syncthreads();   // st visible

#pragma unroll
        for (int s = 0; s < CHK; ++s) {
            // phase A: readlane matvec from own wave's lc regs
            float pa = 0.f, pb = 0.f;
#pragma unroll
            for (int k = 0; k < 32; ++k) {
                const float u = __uint_as_float(
                    __builtin_amdgcn_readlane(__float_as_uint(lc), k));
                pa = fmaf(u, wA[k], pa);
                pb = fmaf(u, wB[k], pb);
            }
            *(float2*)&part[par][wv][d0] = make_float2(pa, pb);
            __syncthreads();   // the ONLY per-step barrier
            // phase B: reduce partials for owned index dd, update state
            if (l < 32) {
                const float fs = part[par][0][dd] + part[par][1][dd]
                               + part[par][2][dd] + part[par][3][dd];
                const float ab = st_ab[(s << 7) + dd];
                const float pf = st_pf[(s << 7) + dd];
                const float fg = 1.f / (1.f + __expf(-(fs + pf)));
                lc = lc * fg + ab;
                lcbuf[s] = lc;
            }
            par ^= 1;
        }
        // ---- dump chunk's lc history into the (consumed) st_ab buffer ----
        // wave w touches only columns [32w,32w+32) — same as its phase-B
        // reads, so no barrier needed before these writes.
        if (l < 32) {
#pragma unroll
            for (int s = 0; s < CHK; ++s)
                st_ab[(s << 7) + dd] = lcbuf[s];
        }
        __syncthreads();   // lc history visible to all waves
        // ---- fused epilogue: wave wv handles rows s = wv, wv+4, ... ----
        for (int s = wv; s < CHK; s += 4) {
            const int t = c * CHK + s;
            if (t >= Tt) break;
            const int qt  = clampi(q_seq[b * Ss + t], 0, NQq - 1);
            const int qt1 = clampi(q_seq[b * Ss + t + 1], 0, NQq - 1);
            const int4 mm = ((const int4*)q2cm)[qt];
            int4 ci = ((const int4*)q2c)[qt1];
            const int c0 = clampi(ci.x, 0, NCc - 1), c1 = clampi(ci.y, 0, NCc - 1);
            const int c2 = clampi(ci.z, 0, NCc - 1), c3 = clampi(ci.w, 0, NCc - 1);
            const float la = st_ab[(s << 7) + l];
            const float lb = st_ab[(s << 7) + 64 + l];
            const float e0a = ldf(Ec, c0 * 128 + l, m), e0b = ldf(Ec, c0 * 128 + 64 + l, m);
            const float e1a = ldf(Ec, c1 * 128 + l, m), e1b = ldf(Ec, c1 * 128 + 64 + l, m);
            const float e2a = ldf(Ec, c2 * 128 + l, m), e2b = ldf(Ec, c2 * 128 + 64 + l, m);
            const float e3a = ldf(Ec, c3 * 128 + l, m), e3b = ldf(Ec, c3 * 128 + 64 + l, m);
            float nl = la * la + lb * lb;
            float d0_ = la * e0a + lb * e0b, n0 = e0a * e0a + e0b * e0b;
            float d1_ = la * e1a + lb * e1b, n1 = e1a * e1a + e1b * e1b;
            float d2_ = la * e2a + lb * e2b, n2 = e2a * e2a + e2b * e2b;
            float d3_ = la * e3a + lb * e3b, n3 = e3a * e3a + e3b * e3b;
#pragma unroll
            for (int sh = 32; sh >= 1; sh >>= 1) {
                nl  += __shfl_xor(nl, sh);
                d0_ += __shfl_xor(d0_, sh); d1_ += __shfl_xor(d1_, sh);
                d2_ += __shfl_xor(d2_, sh); d3_ += __shfl_xor(d3_, sh);
                n0  += __shfl_xor(n0, sh);  n1  += __shfl_xor(n1, sh);
                n2  += __shfl_xor(n2, sh);  n3  += __shfl_xor(n3, sh);
            }
            if (l == 0) {
                const float inl = 1.f / fmaxf(sqrtf(nl), 1e-8f);
                const float accv =
                      (float)mm.x * (0.5f * d0_ * inl / fmaxf(sqrtf(n0), 1e-8f) + 0.5f)
                    + (float)mm.y * (0.5f * d1_ * inl / fmaxf(sqrtf(n1), 1e-8f) + 0.5f)
                    + (float)mm.z * (0.5f * d2_ * inl / fmaxf(sqrtf(n2), 1e-8f) + 0.5f)
                    + (float)mm.w * (0.5f * d3_ * inl / fmaxf(sqrtf(n3), 1e-8f) + 0.5f);
                const float logit = qd10[qt1] * (accv - qdm[qt]);
                stf(out, b * Ss + t, m, 1.f / (1.f + __expf(-logit)));
            }
        }
        // next chunk-top __syncthreads() guards st reuse
    }
#undef LOAD_CHUNK
    if (tid == 0) stf(out, b * Ss + 199, m, 0.f);
}

extern "C" void kernel_launch(void* const* d_in, const int* in_sizes, int n_in,
                              void* d_out, int out_size, void* d_ws, size_t ws_size,
                              hipStream_t stream) {
    (void)in_sizes; (void)n_in; (void)out_size; (void)ws_size;
    const int* q_seq  = (const int*)d_in[0];
    const int* ha_seq = (const int*)d_in[1];
    const int* c_seq  = (const int*)d_in[2];
    const int* it_seq = (const int*)d_in[3];
    const int* ut_seq = (const int*)d_in[4];
    const int* q2c    = (const int*)d_in[5];
    const int* q2cm   = (const int*)d_in[6];
    const void* Eq   = d_in[7];
    const void* Eqd  = d_in[8];
    const void* Ec   = d_in[9];
    const void* Eit  = d_in[10];
    const void* Eut  = d_in[11];
    const void* Eha  = d_in[12];
    const void* Wf   = d_in[13];
    const void* bfu  = d_in[14];
    const void* Wa   = d_in[15];
    const void* ba   = d_in[16];
    const void* Wg   = d_in[17];
    const void* bg   = d_in[18];
    const void* L0   = d_in[19];

    // workspace layout (floats) — ~10.4 MB
    float* ws    = (float*)d_ws;
    float* vA0   = ws;                 // 128 x4
    float* vA1   = vA0 + 128;
    float* vF0   = vA1 + 128;
    float* vF1   = vF0 + 128;
    float* PA_ut = vF1 + 128;          // 12800
    float* PA_ha = PA_ut + 12800;      // 1536
    float* PF_it = PA_ha + 1536;       // 12800
    float* qdm   = PF_it + 12800;      // 10016
    float* qd10  = qdm + 10016;        // 10016
    float* PA_q  = qd10 + 10016;       // 1,280,000
    float* PF_q  = PA_q + 1280000;     // 1,280,000

    hipLaunchKernelGGL(k_prep, dim3(2926), dim3(256), 0, stream,
                       Eq, Eqd, Wf, Wa, Wg, bfu, ba, bg, Eut, Eha, Eit, Ec,
                       q2c, q2cm, vA0, vA1, vF0, vF1,
                       PA_ut, PA_ha, PF_it, qdm, qd10, PA_q, PF_q);
    hipLaunchKernelGGL(k_scan, dim3(Bb), dim3(256), 0, stream,
                       q_seq, ut_seq, ha_seq, it_seq, c_seq, q2c, q2cm,
                       Eq, Ec, Wg, L0,
                       PA_q, PA_ut, PA_ha, PF_q, PF_it,
                       vA0, vA1, vF0, vF1, qdm, qd10, d_out);
}

// Round 14
// 224.535 us; speedup vs baseline: 1.3051x; 1.3051x over previous
//
#include <hip/hip_runtime.h>
#include <hip/hip_bf16.h>

typedef unsigned short u16;

#define Bb  128
#define Ss  200
#define Tt  199   // S-1
#define NQq 10000
#define NCc 500
#define CHK 16    // scan chunk (steps staged per refill)
#define NCH 13    // ceil(199/16)

__device__ inline float bf2f(u16 u) {
    union { unsigned int i; float f; } x;
    x.i = ((unsigned int)u) << 16;
    return x.f;
}

// mode m: 1 = buffers hold fp32, 0 = buffers hold bf16
__device__ inline float ldf(const void* p, int i, int m) {
    if (m) return ((const float*)p)[i];
    return bf2f(((const u16*)p)[i]);
}

__device__ inline void stf(void* p, int i, int m, float v) {
    if (m) ((float*)p)[i] = v;
    else ((__hip_bfloat16*)p)[i] = __float2bfloat16(v);
}

__device__ inline int clampi(int v, int lo, int hi) {
    return v < lo ? lo : (v > hi ? hi : v);
}

__device__ inline float wave_red(float v) {
#pragma unroll
    for (int m = 32; m >= 1; m >>= 1) v += __shfl_xor(v, m);
    return v;
}

__device__ inline float4 f4add(float4 a, float4 b) {
    return make_float4(a.x + b.x, a.y + b.y, a.z + b.z, a.w + b.w);
}
__device__ inline float4 f4fma(float s, float4 a, float4 b) {
    return make_float4(fmaf(s, a.x, b.x), fmaf(s, a.y, b.y),
                       fmaf(s, a.z, b.z), fmaf(s, a.w, b.w));
}

// per-block inline dtype detection: scan first 256 u16 of Eq as bf16.
__device__ inline int detect_mode(const void* Eq) {
    const u16* q = (const u16*)Eq;
    const int l = threadIdx.x & 63;
    float mx = 0.f;
#pragma unroll
    for (int k = 0; k < 4; ++k) {
        float a = fabsf(bf2f(q[l * 4 + k]));
        if (!(a == a)) a = 3.0e38f;
        mx = fmaxf(mx, a);
    }
#pragma unroll
    for (int s = 32; s >= 1; s >>= 1) mx = fmaxf(mx, __shfl_xor(mx, s));
    return (mx > 1.0e6f) ? 1 : 0;
}

// load a flat 4096-element (32x128) tile from a mode-typed matrix into LDS
__device__ inline void load_tile_4096(float* dst, const void* src, int base,
                                      int tid, int m) {
    if (m) {
        const float4* s = (const float4*)((const float*)src + base);
        float4* d = (float4*)dst;
#pragma unroll
        for (int k = 0; k < 4; ++k) d[tid + k * 256] = s[tid + k * 256];
    } else {
        const u16* s = (const u16*)src + base;
#pragma unroll
        for (int k = 0; k < 4; ++k) {
            const int idx = (tid + k * 256) * 4;
            uint2 v = *(const uint2*)(s + idx);
            float* d = dst + idx;
            d[0] = bf2f((u16)(v.x & 0xffff)); d[1] = bf2f((u16)(v.x >> 16));
            d[2] = bf2f((u16)(v.y & 0xffff)); d[3] = bf2f((u16)(v.y >> 16));
        }
    }
}

// ---------------- K1: everything-parallel prep, ONE launch -----------------
// job<313: chained GEMM  PA_q/PF_q = (Eq@Wf_top) @ {WA1, Wg3}  (t32 in LDS)
// 313: vA/vF bias vectors | 314..413: PA_ut/PF_it | 414..425: PA_ha
// 426..2925: per-question qdm/qd10 (inline concept norms)
// 2926..3050: cnorm table (500 concept norms, 4 per block) for p5
__global__ __launch_bounds__(256) void k_prep(
    const void* Eq, const void* Eqd, const void* Wf, const void* Wa, const void* Wg,
    const void* bfu, const void* ba, const void* bg,
    const void* Eut, const void* Eha, const void* Eit, const void* Ec,
    const int* q2c, const int* q2cm,
    float* vA0, float* vA1, float* vF0, float* vF1,
    float* PA_ut, float* PA_ha, float* PF_it, float* qdm, float* qd10,
    float* PA_q, float* PF_q, float* cnorm) {
    const int m = detect_mode(Eq);
    const int job = blockIdx.x, tid = threadIdx.x;
    __shared__ __align__(16) float smem[12416];   // 48.5 KB, partitioned per job
    if (job < 313) {
        float* t32s = smem;            // [32][132]
        float* At   = smem + 4224;     // [32][36]   (stage 1)
        float* BtW  = smem + 5376;     // [32][128]  (stage 1)
        float* Bt0  = smem + 4224;     // [32][128]  (stage 2 overlay)
        float* Bt1  = smem + 8320;     // [32][128]
        const int r0 = job * 32;
        const int tx = tid & 15, ty = tid >> 4;
        // ---- stage 1: t32 = Eq_tile(32x128) @ Wf_top(128x128) ----
        float accT[2][8];
#pragma unroll
        for (int j = 0; j < 2; ++j)
#pragma unroll
            for (int i = 0; i < 8; ++i) accT[j][i] = 0.f;
        for (int ks = 0; ks < 4; ++ks) {
            {   // A tile from Eq: 32 rows x 32 k, 4 elements/thread
                const int row = tid >> 3, seg = tid & 7;
                const int q = clampi(r0 + row, 0, NQq - 1);
                const int ei = q * 128 + ks * 32 + seg * 4;
                float* dst = At + row * 36 + seg * 4;
                if (m) {
                    float4 v = *(const float4*)((const float*)Eq + ei);
                    dst[0] = v.x; dst[1] = v.y; dst[2] = v.z; dst[3] = v.w;
                } else {
                    uint2 v = *(const uint2*)((const u16*)Eq + ei);
                    dst[0] = bf2f((u16)(v.x & 0xffff)); dst[1] = bf2f((u16)(v.x >> 16));
                    dst[2] = bf2f((u16)(v.y & 0xffff)); dst[3] = bf2f((u16)(v.y >> 16));
                }
            }
            load_tile_4096(BtW, Wf, ks * 32 * 128, tid, m);
            __syncthreads();
#pragma unroll
            for (int kk = 0; kk < 32; kk += 4) {
                float a_[2][4];
                *(float4*)&a_[0][0] = *(const float4*)(At + (ty * 2 + 0) * 36 + kk);
                *(float4*)&a_[1][0] = *(const float4*)(At + (ty * 2 + 1) * 36 + kk);
#pragma unroll
                for (int q4 = 0; q4 < 4; ++q4) {
                    float4 b0 = *(const float4*)(BtW + (kk + q4) * 128 + tx * 8);
                    float4 b1 = *(const float4*)(BtW + (kk + q4) * 128 + tx * 8 + 4);
#pragma unroll
                    for (int j = 0; j < 2; ++j) {
                        const float av = a_[j][q4];
                        accT[j][0] += av * b0.x; accT[j][1] += av * b0.y;
                        accT[j][2] += av * b0.z; accT[j][3] += av * b0.w;
                        accT[j][4] += av * b1.x; accT[j][5] += av * b1.y;
                        accT[j][6] += av * b1.z; accT[j][7] += av * b1.w;
                    }
                }
            }
            __syncthreads();
        }
#pragma unroll
        for (int j = 0; j < 2; ++j) {
            const int row = ty * 2 + j;
            *(float4*)(t32s + row * 132 + tx * 8) =
                make_float4(accT[j][0], accT[j][1], accT[j][2], accT[j][3]);
            *(float4*)(t32s + row * 132 + tx * 8 + 4) =
                make_float4(accT[j][4], accT[j][5], accT[j][6], accT[j][7]);
        }
        __syncthreads();
        // ---- stage 2: PA = t32 @ WA1, PF = t32 @ Wg3 ----
        float acc0[2][8], acc1[2][8];
#pragma unroll
        for (int j = 0; j < 2; ++j)
#pragma unroll
            for (int i = 0; i < 8; ++i) { acc0[j][i] = 0.f; acc1[j][i] = 0.f; }
        for (int ks2 = 0; ks2 < 4; ++ks2) {
            load_tile_4096(Bt0, Wa, ks2 * 32 * 128, tid, m);
            load_tile_4096(Bt1, Wg, 256 * 128 + ks2 * 32 * 128, tid, m);
            __syncthreads();
#pragma unroll
            for (int kk = 0; kk < 32; kk += 4) {
                float a_[2][4];
                *(float4*)&a_[0][0] =
                    *(const float4*)(t32s + (ty * 2 + 0) * 132 + ks2 * 32 + kk);
                *(float4*)&a_[1][0] =
                    *(const float4*)(t32s + (ty * 2 + 1) * 132 + ks2 * 32 + kk);
#pragma unroll
                for (int q4 = 0; q4 < 4; ++q4) {
                    float4 b0 = *(const float4*)(Bt0 + (kk + q4) * 128 + tx * 8);
                    float4 b1 = *(const float4*)(Bt0 + (kk + q4) * 128 + tx * 8 + 4);
                    float4 c0 = *(const float4*)(Bt1 + (kk + q4) * 128 + tx * 8);
                    float4 c1 = *(const float4*)(Bt1 + (kk + q4) * 128 + tx * 8 + 4);
#pragma unroll
                    for (int j = 0; j < 2; ++j) {
                        const float av = a_[j][q4];
                        acc0[j][0] += av * b0.x; acc0[j][1] += av * b0.y;
                        acc0[j][2] += av * b0.z; acc0[j][3] += av * b0.w;
                        acc0[j][4] += av * b1.x; acc0[j][5] += av * b1.y;
                        acc0[j][6] += av * b1.z; acc0[j][7] += av * b1.w;
                        acc1[j][0] += av * c0.x; acc1[j][1] += av * c0.y;
                        acc1[j][2] += av * c0.z; acc1[j][3] += av * c0.w;
                        acc1[j][4] += av * c1.x; acc1[j][5] += av * c1.y;
                        acc1[j][6] += av * c1.z; acc1[j][7] += av * c1.w;
                    }
                }
            }
            __syncthreads();
        }
#pragma unroll
        for (int j = 0; j < 2; ++j) {
            const int q = r0 + ty * 2 + j;
            if (q < NQq) {
                float* oa = PA_q + q * 128 + tx * 8;
                float* of = PF_q + q * 128 + tx * 8;
#pragma unroll
                for (int i = 0; i < 8; ++i) { oa[i] = acc0[j][i]; of[i] = acc1[j][i]; }
            }
        }
    } else if (job == 313) {    // vA0/vA1 (threads<128), vF0/vF1 (>=128)
        const int col = tid & 127;
        if (tid < 128) {
            float s = 0.f;
            for (int r2 = 0; r2 < 128; ++r2) s += ldf(Wf, (128 + r2) * 128 + col, m);
            smem[col] = s;      // cs2
        }
        __syncthreads();
        float a0 = 0.f, a1 = 0.f;
        if (tid < 128) {
            for (int j = 0; j < 128; ++j) {
                const float wv = ldf(Wa, j * 128 + col, m);
                a0 += ldf(bfu, j, m) * wv;
                a1 += smem[j] * wv;
            }
            vA0[col] = a0 + ldf(ba, col, m);
            vA1[col] = a1;
        } else {
            for (int j = 0; j < 128; ++j) {
                const float wv = ldf(Wg, (256 + j) * 128 + col, m);
                a0 += ldf(bfu, j, m) * wv;
                a1 += smem[j] * wv;
            }
            vF0[col] = a0 + ldf(bg, col, m);
            vF1[col] = a1;
        }
    } else if (job < 414) {     // PA_ut row (threads<128) / PF_it row (>=128)
        const int r = job - 314, col = tid & 127;
        float acc = 0.f;
        if (tid < 128) {
            for (int j = 0; j < 128; ++j)
                acc += ldf(Eut, r * 128 + j, m) * ldf(Wa, (128 + j) * 128 + col, m);
            PA_ut[r * 128 + col] = acc;
        } else {
            for (int j = 0; j < 128; ++j)
                acc += ldf(Eit, r * 128 + j, m) * ldf(Wg, (128 + j) * 128 + col, m);
            PF_it[r * 128 + col] = acc;
        }
    } else if (job < 426) {     // PA_ha rows 0..11
        const int r = job - 414;
        if (tid < 128) {
            float acc = 0.f;
            for (int j = 0; j < 128; ++j)
                acc += ldf(Eha, r * 128 + j, m) * ldf(Wa, (256 + j) * 128 + tid, m);
            PA_ha[r * 128 + tid] = acc;
        }
    } else if (job < 2926) {    // p2q with inline concept norms
        const int wv = tid >> 6, lane = tid & 63;
        const int q = (job - 426) * 4 + wv;   // 0..9999
        const float qa = ldf(Eq, q * 128 + lane, m);
        const float qb = ldf(Eq, q * 128 + 64 + lane, m);
        const float nqc = fmaxf(sqrtf(wave_red(qa * qa + qb * qb)), 1e-8f);
        const int4 cc = ((const int4*)q2c)[q];
        const int4 mm = ((const int4*)q2cm)[q];
        const int cks[4] = {clampi(cc.x, 0, NCc - 1), clampi(cc.y, 0, NCc - 1),
                            clampi(cc.z, 0, NCc - 1), clampi(cc.w, 0, NCc - 1)};
        const int ms[4]  = {mm.x, mm.y, mm.z, mm.w};
        float qs = 0.f;
#pragma unroll
        for (int k = 0; k < 4; ++k) {
            const int ck = cks[k];
            const float ea = ldf(Ec, ck * 128 + lane, m);
            const float eb = ldf(Ec, ck * 128 + 64 + lane, m);
            const float dot = wave_red(qa * ea + qb * eb);
            const float nn = fmaxf(sqrtf(wave_red(ea * ea + eb * eb)), 1e-8f);
            qs += (float)ms[k] * (0.5f * dot / (nqc * nn) + 0.5f);
        }
        if (lane == 0) {
            qdm[q] = qs;
            qd10[q] = 10.f / (1.f + __expf(-ldf(Eqd, q, m)));
        }
    } else {                    // cnorm table: 4 concepts per block (one/wave)
        const int wv = tid >> 6, lane = tid & 63;
        const int c = (job - 2926) * 4 + wv;  // 0..499
        if (c < NCc) {
            const float ea = ldf(Ec, c * 128 + lane, m);
            const float eb = ldf(Ec, c * 128 + 64 + lane, m);
            const float nn = wave_red(ea * ea + eb * eb);
            if (lane == 0) cnorm[c] = fmaxf(sqrtf(nn), 1e-8f);
        }
    }
}

// ---------------- K2: scan — R8-exact structure (77 us plateau) ------------
// Wave w owns i-range AND state lc[32w..32w+32). lp broadcast via readlane
// from own wave's lc regs. One barrier per step; chunk gathers at chunk top.
__global__ __launch_bounds__(256) void p4_scan(
    const int* q_seq, const int* ut_seq, const int* ha_seq, const int* it_seq,
    const int* c_seq,
    const void* Eq, const void* Wg, const void* L0,
    const float* PA_q, const float* PA_ut, const float* PA_ha,
    const float* PF_q, const float* PF_it,
    const float* vA0, const float* vA1, const float* vF0, const float* vF1,
    float* lc_seq) {
    const int m = detect_mode(Eq);
    const int b = blockIdx.x;
    const int tid = threadIdx.x;
    const int wv = tid >> 6, l = tid & 63;
    const int d0 = 2 * l;
    const int ib = wv << 5;
    const int dd = ib + (l & 31);

    __shared__ float part[2][4][128];
    __shared__ float st_ab[CHK * 128];
    __shared__ float st_pf[CHK * 128];

    float wA[32], wB[32];
#pragma unroll
    for (int k = 0; k < 32; ++k) {
        wA[k] = ldf(Wg, (ib + k) * 128 + d0, m);
        wB[k] = ldf(Wg, (ib + k) * 128 + d0 + 1, m);
    }
    float lc = (l < 32) ? ldf(L0, b * 128 + dd, m) : 0.f;

    const int srow = tid >> 4, seg = tid & 15;
    const int off8 = seg * 8;
    const float4 A0a = *(const float4*)(vA0 + off8), A0b = *(const float4*)(vA0 + off8 + 4);
    const float4 A1a = *(const float4*)(vA1 + off8), A1b = *(const float4*)(vA1 + off8 + 4);
    const float4 F0a = *(const float4*)(vF0 + off8), F0b = *(const float4*)(vF0 + off8 + 4);
    const float4 F1a = *(const float4*)(vF1 + off8), F1b = *(const float4*)(vF1 + off8 + 4);

    float4 qa0, qa1, ua0, ua1, ga0, ga1, qf0, qf1, if0, if1;
    float cf;
#define LOAD_CHUNK(C)                                                          \
    {                                                                          \
        int tt = (C) * CHK + srow; if (tt > Tt - 1) tt = Tt - 1;               \
        const int base = b * Ss + tt;                                          \
        const int qt = clampi(q_seq[base], 0, NQq - 1);                        \
        const int ut = clampi(ut_seq[base], 0, 99);                            \
        const int ha = clampi(ha_seq[base], 0, 11);                            \
        const int it = clampi(it_seq[base], 0, 99);                            \
        cf = (float)c_seq[base];                                               \
        const float* pq = PA_q + qt * 128 + off8;                              \
        qa0 = *(const float4*)pq; qa1 = *(const float4*)(pq + 4);              \
        const float* pu = PA_ut + ut * 128 + off8;                             \
        ua0 = *(const float4*)pu; ua1 = *(const float4*)(pu + 4);              \
        const float* ph = PA_ha + ha * 128 + off8;                             \
        ga0 = *(const float4*)ph; ga1 = *(const float4*)(ph + 4);              \
        const float* pf = PF_q + qt * 128 + off8;                              \
        qf0 = *(const float4*)pf; qf1 = *(const float4*)(pf + 4);              \
        const float* pi = PF_it + it * 128 + off8;                             \
        if0 = *(const float4*)pi; if1 = *(const float4*)(pi + 4);              \
    }

    LOAD_CHUNK(0)
    float lcbuf[CHK];
    int par = 0;

    for (int c = 0; c < NCH; ++c) {
        __syncthreads();   // prior chunk's st readers done
        {   // publish staged chunk c
            float4 ab0 = f4fma(cf, A1a, f4add(f4add(qa0, ua0), f4add(ga0, A0a)));
            float4 ab1 = f4fma(cf, A1b, f4add(f4add(qa1, ua1), f4add(ga1, A0b)));
            float4 pf0 = f4fma(cf, F1a, f4add(qf0, f4add(if0, F0a)));
            float4 pf1 = f4fma(cf, F1b, f4add(qf1, f4add(if1, F0b)));
            float4* sa = (float4*)(st_ab + srow * 128 + off8);
            sa[0] = ab0; sa[1] = ab1;
            float4* sp = (float4*)(st_pf + srow * 128 + off8);
            sp[0] = pf0; sp[1] = pf1;
        }
        if (c + 1 < NCH) LOAD_CHUNK(c + 1)
        __syncthreads();   // st visible

#pragma unroll
        for (int s = 0; s < CHK; ++s) {
            // phase A: readlane matvec from own wave's lc regs
            float pa = 0.f, pb = 0.f;
#pragma unroll
            for (int k = 0; k < 32; ++k) {
                const float u = __uint_as_float(
                    __builtin_amdgcn_readlane(__float_as_uint(lc), k));
                pa = fmaf(u, wA[k], pa);
                pb = fmaf(u, wB[k], pb);
            }
            *(float2*)&part[par][wv][d0] = make_float2(pa, pb);
            __syncthreads();   // the ONLY per-step barrier
            // phase B: reduce partials for owned index dd, update state
            if (l < 32) {
                const float fs = part[par][0][dd] + part[par][1][dd]
                               + part[par][2][dd] + part[par][3][dd];
                const float ab = st_ab[(s << 7) + dd];
                const float pf = st_pf[(s << 7) + dd];
                const float fg = 1.f / (1.f + __expf(-(fs + pf)));
                lc = lc * fg + ab;
                lcbuf[s] = lc;
            }
            par ^= 1;
        }
        // flush lc history for chunk c
        if (l < 32) {
#pragma unroll
            for (int s = 0; s < CHK; ++s) {
                const int t = c * CHK + s;
                if (t < Tt)
                    lc_seq[((long)t * 128 + b) * 128 + dd] = lcbuf[s];
            }
        }
    }
#undef LOAD_CHUNK
}

// ---------------- K3: cosine/logit epilogue (cnorm table, 5 chains) --------
__global__ __launch_bounds__(256) void p5_out(
    const int* q_seq, const int* q2c, const int* q2cm,
    const float* lc_seq, const float* qdm, const float* qd10,
    const float* cnorm, const void* Eq, const void* Ec, void* out) {
    const int m = detect_mode(Eq);
    const int wv = threadIdx.x >> 6, lane = threadIdx.x & 63;
    const int r = blockIdx.x * 4 + wv;  // 6368*4 == 25472 == Tt*Bb
    const int t = r >> 7, b = r & 127;
    const int qt  = clampi(q_seq[b * Ss + t], 0, NQq - 1);
    const int qt1 = clampi(q_seq[b * Ss + t + 1], 0, NQq - 1);
    const int4 mm = ((const int4*)q2cm)[qt];
    int4 ci = ((const int4*)q2c)[qt1];
    const int c0 = clampi(ci.x, 0, NCc - 1), c1 = clampi(ci.y, 0, NCc - 1);
    const int c2 = clampi(ci.z, 0, NCc - 1), c3 = clampi(ci.w, 0, NCc - 1);
    const float la = lc_seq[(long)r * 128 + lane];
    const float lb = lc_seq[(long)r * 128 + 64 + lane];
    float nl = la * la + lb * lb;
    float d0 = la * ldf(Ec, c0 * 128 + lane, m) + lb * ldf(Ec, c0 * 128 + 64 + lane, m);
    float d1 = la * ldf(Ec, c1 * 128 + lane, m) + lb * ldf(Ec, c1 * 128 + 64 + lane, m);
    float d2 = la * ldf(Ec, c2 * 128 + lane, m) + lb * ldf(Ec, c2 * 128 + 64 + lane, m);
    float d3 = la * ldf(Ec, c3 * 128 + lane, m) + lb * ldf(Ec, c3 * 128 + 64 + lane, m);
#pragma unroll
    for (int s = 32; s >= 1; s >>= 1) {
        nl += __shfl_xor(nl, s);
        d0 += __shfl_xor(d0, s); d1 += __shfl_xor(d1, s);
        d2 += __shfl_xor(d2, s); d3 += __shfl_xor(d3, s);
    }
    if (lane == 0) {
        const float inl = 1.f / fmaxf(sqrtf(nl), 1e-8f);
        const float accv =
              (float)mm.x * (0.5f * d0 * inl / cnorm[c0] + 0.5f)
            + (float)mm.y * (0.5f * d1 * inl / cnorm[c1] + 0.5f)
            + (float)mm.z * (0.5f * d2 * inl / cnorm[c2] + 0.5f)
            + (float)mm.w * (0.5f * d3 * inl / cnorm[c3] + 0.5f);
        const float logit = qd10[qt1] * (accv - qdm[qt]);
        stf(out, b * Ss + t, m, 1.f / (1.f + __expf(-logit)));
        if (t == 0) stf(out, b * Ss + 199, m, 0.f);
    }
}

extern "C" void kernel_launch(void* const* d_in, const int* in_sizes, int n_in,
                              void* d_out, int out_size, void* d_ws, size_t ws_size,
                              hipStream_t stream) {
    (void)in_sizes; (void)n_in; (void)out_size; (void)ws_size;
    const int* q_seq  = (const int*)d_in[0];
    const int* ha_seq = (const int*)d_in[1];
    const int* c_seq  = (const int*)d_in[2];
    const int* it_seq = (const int*)d_in[3];
    const int* ut_seq = (const int*)d_in[4];
    const int* q2c    = (const int*)d_in[5];
    const int* q2cm   = (const int*)d_in[6];
    const void* Eq   = d_in[7];
    const void* Eqd  = d_in[8];
    const void* Ec   = d_in[9];
    const void* Eit  = d_in[10];
    const void* Eut  = d_in[11];
    const void* Eha  = d_in[12];
    const void* Wf   = d_in[13];
    const void* bfu  = d_in[14];
    const void* Wa   = d_in[15];
    const void* ba   = d_in[16];
    const void* Wg   = d_in[17];
    const void* bg   = d_in[18];
    const void* L0   = d_in[19];

    // workspace layout (floats) — ~23.4 MB
    float* ws    = (float*)d_ws;
    float* vA0   = ws;                 // 128 x4
    float* vA1   = vA0 + 128;
    float* vF0   = vA1 + 128;
    float* vF1   = vF0 + 128;
    float* cnorm = vF1 + 128;          // 512 (500 used)
    float* PA_ut = cnorm + 512;        // 12800
    float* PA_ha = PA_ut + 12800;      // 1536
    float* PF_it = PA_ha + 1536;       // 12800
    float* qdm   = PF_it + 12800;      // 10016
    float* qd10  = qdm + 10016;        // 10016
    float* PA_q  = qd10 + 10016;       // 1,280,000
    float* PF_q  = PA_q + 1280000;     // 1,280,000
    float* lc_seq= PF_q + 1280000;     // 3,260,416

    hipLaunchKernelGGL(k_prep, dim3(3051), dim3(256), 0, stream,
                       Eq, Eqd, Wf, Wa, Wg, bfu, ba, bg, Eut, Eha, Eit, Ec,
                       q2c, q2cm, vA0, vA1, vF0, vF1,
                       PA_ut, PA_ha, PF_it, qdm, qd10, PA_q, PF_q, cnorm);
    hipLaunchKernelGGL(p4_scan, dim3(Bb), dim3(256), 0, stream,
                       q_seq, ut_seq, ha_seq, it_seq, c_seq, Eq, Wg, L0,
                       PA_q, PA_ut, PA_ha, PF_q, PF_it,
                       vA0, vA1, vF0, vF1, lc_seq);
    hipLaunchKernelGGL(p5_out, dim3(Tt * Bb / 4), dim3(256), 0, stream,
                       q_seq, q2c, q2cm, lc_seq, qdm, qd10, cnorm, Eq, Ec, d_out);
}